// Round 3
// baseline (394.939 us; speedup 1.0000x reference)
//
#include <hip/hip_runtime.h>
#include <hip/hip_bf16.h>
#include <stdint.h>

// B=8, T=1024, D=1024, H=8, d=128, M=8192.
// ws layout (shorts): xb[8388608] | wb[3145728] | Qh[8388608] | Kh[8388608] | VhT[8388608]
// Qh/Kh: [h][b][t][dd] bf16 (Qh pre-scaled by 1/sqrt(128)); VhT: [h][b][dd][t] bf16.

typedef __attribute__((ext_vector_type(8))) short short8;
typedef __attribute__((ext_vector_type(4))) float floatx4;

__device__ __forceinline__ short f2bf(float f) {
    union { float f; uint32_t u; } v; v.f = f;
    uint32_t r = v.u + 0x7fffu + ((v.u >> 16) & 1u);   // RNE
    return (short)(r >> 16);
}

__device__ __forceinline__ void load_lds_16B(const void* g, void* l) {
    __builtin_amdgcn_global_load_lds(
        (const __attribute__((address_space(1))) void*)g,
        (__attribute__((address_space(3))) void*)l, 16, 0, 0);
}

// ---------------------------------------------------------------------------
// fp32 -> bf16 cast, 8 elems/thread
// ---------------------------------------------------------------------------
__global__ __launch_bounds__(256) void cast_kernel(
    const float* __restrict__ src, short* __restrict__ dst, int n8)
{
    int i = blockIdx.x * 256 + threadIdx.x;
    if (i >= n8) return;
    float4 a = *(const float4*)(src + i * 8);
    float4 b = *(const float4*)(src + i * 8 + 4);
    short8 o;
    o[0] = f2bf(a.x); o[1] = f2bf(a.y); o[2] = f2bf(a.z); o[3] = f2bf(a.w);
    o[4] = f2bf(b.x); o[5] = f2bf(b.y); o[6] = f2bf(b.z); o[7] = f2bf(b.w);
    *(short8*)(dst + i * 8) = o;
}

// ---------------------------------------------------------------------------
// QKV GEMM (m97 structure) + LDS-staged coalesced epilogue.
// C[m][n] = sum_k xb[m][k] * wb[n][k];  n in [0,3072) selects Q/K/V.
// ---------------------------------------------------------------------------
__global__ __launch_bounds__(256) void qkv_gemm_kernel(
    const short* __restrict__ xb, const short* __restrict__ wb,
    short* __restrict__ Qh, short* __restrict__ Kh, short* __restrict__ VhT)
{
    __shared__ short As[128 * 32];
    __shared__ short Bs[128 * 32];
    __shared__ short Cs[8704];       // 64x132 (Q/K) or 128x68 transposed (V)

    const int tid = threadIdx.x;
    const int m0 = blockIdx.y * 128;
    const int n0 = blockIdx.x * 128;
    const int wave = tid >> 6;
    const int lane = tid & 63;
    const int wm = (wave >> 1) * 64;
    const int wn = (wave & 1) * 64;
    const int l16 = lane & 15;
    const int quad = lane >> 4;

    const int srow = lane >> 2;
    const int scol = (lane & 3) * 8;

    floatx4 zero = {0.0f, 0.0f, 0.0f, 0.0f};
    floatx4 acc[4][4];
    for (int i = 0; i < 4; ++i)
        for (int j = 0; j < 4; ++j) acc[i][j] = zero;

    for (int k0 = 0; k0 < 1024; k0 += 32) {
        __syncthreads();
        #pragma unroll
        for (int c = 0; c < 4; ++c) {
            int chunk = wave * 4 + c;
            if (chunk < 8) {
                int row = chunk * 16 + srow;
                load_lds_16B(xb + (m0 + row) * 1024 + k0 + scol, &As[chunk * 512]);
            } else {
                int row = (chunk - 8) * 16 + srow;
                load_lds_16B(wb + (n0 + row) * 1024 + k0 + scol, &Bs[(chunk - 8) * 512]);
            }
        }
        __syncthreads();

        short8 a[4], b[4];
        #pragma unroll
        for (int i = 0; i < 4; ++i)
            a[i] = *(const short8*)&As[(wm + i * 16 + l16) * 32 + quad * 8];
        #pragma unroll
        for (int j = 0; j < 4; ++j)
            b[j] = *(const short8*)&Bs[(wn + j * 16 + l16) * 32 + quad * 8];
        #pragma unroll
        for (int i = 0; i < 4; ++i)
            #pragma unroll
            for (int j = 0; j < 4; ++j)
                acc[i][j] = __builtin_amdgcn_mfma_f32_16x16x32_bf16(a[i], b[j], acc[i][j], 0, 0, 0);
    }

    const float qscale = 0.08838834764831845f;  // 1/sqrt(128), folded into Q
    const int f0 = n0 & 1023;
    const int h = f0 >> 7;
    const bool isV = (n0 >= 2048);
    const float sc = (n0 < 1024) ? qscale : 1.0f;
    short* dst = (n0 < 1024) ? Qh : Kh;

    #pragma unroll
    for (int half = 0; half < 2; ++half) {
        __syncthreads();
        if ((wave >> 1) == half) {
            #pragma unroll
            for (int i = 0; i < 4; ++i)
                #pragma unroll
                for (int j = 0; j < 4; ++j)
                    #pragma unroll
                    for (int p = 0; p < 4; ++p) {
                        int mr = i * 16 + quad * 4 + p;        // 0..63
                        int c = wn + j * 16 + l16;             // 0..127
                        short v = f2bf(acc[i][j][p] * sc);
                        if (isV) Cs[c * 68 + mr] = v;          // transposed
                        else     Cs[mr * 132 + c] = v;
                    }
        }
        __syncthreads();
        if (!isV) {
            // rows: contiguous 128 dd per (b,t); 16B stores
            #pragma unroll
            for (int jj = 0; jj < 4; ++jj) {
                int idx = tid + jj * 256;
                int row = idx >> 4;                // 0..63
                int chunk = idx & 15;
                int m = m0 + half * 64 + row;
                int bb = m >> 10, t = m & 1023;
                *(short8*)&dst[((h * 8 + bb) * 1024 + t) * 128 + chunk * 8] =
                    *(const short8*)&Cs[row * 132 + chunk * 8];
            }
        } else {
            // VhT[h][b][dd][t]: 64 contiguous t per dd row this half
            int m = m0 + half * 64;
            int bb = m >> 10, t = m & 1023;
            #pragma unroll
            for (int jj = 0; jj < 4; ++jj) {
                int idx = tid + jj * 256;
                int dd = idx >> 3;                 // 0..127
                int chunk = idx & 7;
                *(short8*)&VhT[((h * 8 + bb) * 128 + dd) * 1024 + t + chunk * 8] =
                    *(const short8*)&Cs[dd * 68 + chunk * 8];
            }
        }
    }
}

// ---------------------------------------------------------------------------
// Flash attention v3: wave-independent, ZERO barriers. Each wave owns 16
// q-rows; K/V B-fragments loaded directly from global (16B/lane, full-line
// utilization; L1/L2-hot). Only LDS use: per-wave P C->A transform.
// No running max (scores bounded; masked lanes underflow to 0 exactly like
// ref; row 1023 skips the -10000 add -> softmax shift-invariance).
// ---------------------------------------------------------------------------
#define LDP 68

__global__ __launch_bounds__(256) void attn_kernel(
    const short* __restrict__ Qh, const short* __restrict__ Kh,
    const short* __restrict__ VhT, const float* __restrict__ mask,
    float* __restrict__ out)
{
    __shared__ short Ps[4 * 16 * LDP];        // per-wave private regions

    const int tid = threadIdx.x;
    const int qt = blockIdx.x;                // 0..15
    const int hb = blockIdx.y;                // 0..63
    const int h = hb >> 3, b = hb & 7;

    const int wave = tid >> 6;
    const int lane = tid & 63;
    const int l16 = lane & 15;
    const int quad = lane >> 4;

    const int q16 = qt * 4 + wave;            // 0..63, 16 q-rows per wave
    const int q0 = q16 * 16;

    const int base = hb * 131072;
    const short* Qp = Qh + base;
    const short* Kp = Kh + base;
    const short* VTp = VhT + base;
    short* Pw = &Ps[wave * 16 * LDP];

    // Q fragments (A-layout) straight from global (bf16, pre-scaled)
    short8 aq[4];
    #pragma unroll
    for (int kk = 0; kk < 4; ++kk)
        aq[kk] = *(const short8*)(Qp + (q0 + l16) * 128 + kk * 32 + quad * 8);

    floatx4 zero = {0.0f, 0.0f, 0.0f, 0.0f};
    floatx4 o_acc[8];
    #pragma unroll
    for (int n = 0; n < 8; ++n) o_acc[n] = zero;
    float l_run[4] = {0.0f, 0.0f, 0.0f, 0.0f};

    const int kt_start = (q16 == 63) ? 0 : qt;

    for (int kt = kt_start; kt < 16; ++kt) {
        // S = Q K^T  (B-frags direct from global)
        floatx4 s_acc[4];
        #pragma unroll
        for (int sub = 0; sub < 4; ++sub) {
            s_acc[sub] = zero;
            #pragma unroll
            for (int kk = 0; kk < 4; ++kk) {
                short8 bk = *(const short8*)(Kp + (kt * 64 + sub * 16 + l16) * 128 + kk * 32 + quad * 8);
                s_acc[sub] = __builtin_amdgcn_mfma_f32_16x16x32_bf16(aq[kk], bk, s_acc[sub], 0, 0, 0);
            }
        }

        // mask + exp (no max subtraction), l accumulation, P -> per-wave LDS
        #pragma unroll
        for (int sub = 0; sub < 4; ++sub)
            #pragma unroll
            for (int p = 0; p < 4; ++p) {
                int qg = q0 + quad * 4 + p;
                int kg = kt * 64 + sub * 16 + l16;
                float s = s_acc[sub][p];
                if (kg <= qg && qg != 1023) s -= 10000.0f;
                float e = __expf(s);
                l_run[p] += e;
                Pw[(quad * 4 + p) * LDP + sub * 16 + l16] = f2bf(e);
            }

        // O += P @ V  (V B-frags direct from global VhT)
        #pragma unroll
        for (int kk2 = 0; kk2 < 2; ++kk2) {
            short8 ap = *(const short8*)&Pw[l16 * LDP + kk2 * 32 + quad * 8];
            #pragma unroll
            for (int n = 0; n < 8; ++n) {
                short8 bv = *(const short8*)(VTp + (n * 16 + l16) * 1024 + kt * 64 + kk2 * 32 + quad * 8);
                o_acc[n] = __builtin_amdgcn_mfma_f32_16x16x32_bf16(ap, bv, o_acc[n], 0, 0, 0);
            }
        }
    }

    // reduce l across the 16 col-lanes of each row
    #pragma unroll
    for (int off = 8; off >= 1; off >>= 1)
        #pragma unroll
        for (int p = 0; p < 4; ++p)
            l_run[p] += __shfl_xor(l_run[p], off);

    #pragma unroll
    for (int p = 0; p < 4; ++p) {
        int qg = q0 + quad * 4 + p;
        float s = (1.0f / l_run[p]) * mask[b * 1024 + qg];
        #pragma unroll
        for (int n = 0; n < 8; ++n)
            out[(b * 1024 + qg) * 1024 + h * 128 + n * 16 + l16] = o_acc[n][p] * s;
    }
}

// ---------------------------------------------------------------------------
extern "C" void kernel_launch(void* const* d_in, const int* in_sizes, int n_in,
                              void* d_out, int out_size, void* d_ws, size_t ws_size,
                              hipStream_t stream) {
    const float* x    = (const float*)d_in[0];
    const float* mask = (const float*)d_in[1];
    const float* Wq   = (const float*)d_in[2];
    const float* Wk   = (const float*)d_in[3];
    const float* Wv   = (const float*)d_in[4];
    float* out = (float*)d_out;

    short* xb  = (short*)d_ws;            // 8388608
    short* wb  = xb + 8388608;            // 3145728 (Wq|Wk|Wv)
    short* Qh  = wb + 3145728;            // 8388608
    short* Kh  = Qh + 8388608;
    short* VhT = Kh + 8388608;

    cast_kernel<<<4096, 256, 0, stream>>>(x, xb, 1048576);
    cast_kernel<<<512, 256, 0, stream>>>(Wq, wb, 131072);
    cast_kernel<<<512, 256, 0, stream>>>(Wk, wb + 1048576, 131072);
    cast_kernel<<<512, 256, 0, stream>>>(Wv, wb + 2097152, 131072);
    qkv_gemm_kernel<<<dim3(24, 64), 256, 0, stream>>>(xb, wb, Qh, Kh, VhT);
    attn_kernel<<<dim3(16, 64), 256, 0, stream>>>(Qh, Kh, VhT, mask, out);
}

// Round 4
// 262.138 us; speedup vs baseline: 1.5066x; 1.5066x over previous
//
#include <hip/hip_runtime.h>
#include <hip/hip_bf16.h>
#include <stdint.h>

// B=8, T=1024, D=1024, H=8, d=128, M=8192.
// ws (shorts): xb[8388608] | wb[3145728] | Qh[8388608] | Kh[8388608] | VhT[8388608]
// Qh/Kh: [h][b][t][dd] bf16 (Qh pre-scaled by 1/sqrt(128)); VhT: [h][b][dd][t] bf16.

typedef __attribute__((ext_vector_type(8))) short short8;
typedef __attribute__((ext_vector_type(4))) float floatx4;

__device__ __forceinline__ short f2bf(float f) {
    union { float f; uint32_t u; } v; v.f = f;
    uint32_t r = v.u + 0x7fffu + ((v.u >> 16) & 1u);   // RNE
    return (short)(r >> 16);
}

__device__ __forceinline__ void load_lds_16B(const void* g, void* l) {
    __builtin_amdgcn_global_load_lds(
        (const __attribute__((address_space(1))) void*)g,
        (__attribute__((address_space(3))) void*)l, 16, 0, 0);
}

// ---------------------------------------------------------------------------
// fp32 -> bf16 casts
// ---------------------------------------------------------------------------
__global__ __launch_bounds__(256) void cast_kernel(
    const float* __restrict__ src, short* __restrict__ dst, int n8)
{
    int i = blockIdx.x * 256 + threadIdx.x;
    if (i >= n8) return;
    float4 a = *(const float4*)(src + i * 8);
    float4 b = *(const float4*)(src + i * 8 + 4);
    short8 o;
    o[0] = f2bf(a.x); o[1] = f2bf(a.y); o[2] = f2bf(a.z); o[3] = f2bf(a.w);
    o[4] = f2bf(b.x); o[5] = f2bf(b.y); o[6] = f2bf(b.z); o[7] = f2bf(b.w);
    *(short8*)(dst + i * 8) = o;
}

__global__ __launch_bounds__(256) void cast3_kernel(
    const float* __restrict__ w0, const float* __restrict__ w1,
    const float* __restrict__ w2, short* __restrict__ dst)
{
    int sel = blockIdx.x >> 9;                  // 0,1,2
    int blk = blockIdx.x & 511;
    const float* src = (sel == 0) ? w0 : ((sel == 1) ? w1 : w2);
    int i = blk * 256 + threadIdx.x;            // < 131072
    float4 a = *(const float4*)(src + i * 8);
    float4 b = *(const float4*)(src + i * 8 + 4);
    short8 o;
    o[0] = f2bf(a.x); o[1] = f2bf(a.y); o[2] = f2bf(a.z); o[3] = f2bf(a.w);
    o[4] = f2bf(b.x); o[5] = f2bf(b.y); o[6] = f2bf(b.z); o[7] = f2bf(b.w);
    *(short8*)(dst + sel * 1048576 + i * 8) = o;
}

// ---------------------------------------------------------------------------
// QKV GEMM, m97 structure + double-buffered prefetch.
// C[m][n] = sum_k xb[m][k] * wb[n][k];  n in [0,3072) selects Q/K/V.
// ---------------------------------------------------------------------------
__global__ __launch_bounds__(256) void qkv_gemm_kernel(
    const short* __restrict__ xb, const short* __restrict__ wb,
    short* __restrict__ Qh, short* __restrict__ Kh, short* __restrict__ VhT)
{
    __shared__ short As[2][4096];    // [buf][row 128][32]
    __shared__ short Bs[2][4096];
    __shared__ short Cs[8704];       // epilogue: 64x132 (Q/K) or 128x68 T (V)

    const int tid = threadIdx.x;
    const int m0 = blockIdx.y * 128;
    const int n0 = blockIdx.x * 128;
    const int wave = tid >> 6;
    const int lane = tid & 63;
    const int wm = (wave >> 1) * 64;
    const int wn = (wave & 1) * 64;
    const int l16 = lane & 15;
    const int quad = lane >> 4;
    const int srow = lane >> 2;
    const int scol = (lane & 3) * 8;

    floatx4 zero = {0.0f, 0.0f, 0.0f, 0.0f};
    floatx4 acc[4][4];
    for (int i = 0; i < 4; ++i)
        for (int j = 0; j < 4; ++j) acc[i][j] = zero;

    // stage k-slice k0 into buffer bf
    auto stage = [&](int k0, int bf) {
        #pragma unroll
        for (int c = 0; c < 4; ++c) {
            int chunk = wave * 4 + c;            // wave-uniform
            if (chunk < 8)
                load_lds_16B(xb + (m0 + chunk * 16 + srow) * 1024 + k0 + scol,
                             &As[bf][chunk * 512]);
            else
                load_lds_16B(wb + (n0 + (chunk - 8) * 16 + srow) * 1024 + k0 + scol,
                             &Bs[bf][(chunk - 8) * 512]);
        }
    };

    stage(0, 0);
    int buf = 0;
    for (int k0 = 0; k0 < 1024; k0 += 32) {
        __syncthreads();                          // buf ready (loads issued last iter)
        if (k0 + 32 < 1024) stage(k0 + 32, buf ^ 1);

        short8 a[4], b[4];
        #pragma unroll
        for (int i = 0; i < 4; ++i)
            a[i] = *(const short8*)&As[buf][(wm + i * 16 + l16) * 32 + quad * 8];
        #pragma unroll
        for (int j = 0; j < 4; ++j)
            b[j] = *(const short8*)&Bs[buf][(wn + j * 16 + l16) * 32 + quad * 8];
        #pragma unroll
        for (int i = 0; i < 4; ++i)
            #pragma unroll
            for (int j = 0; j < 4; ++j)
                acc[i][j] = __builtin_amdgcn_mfma_f32_16x16x32_bf16(a[i], b[j], acc[i][j], 0, 0, 0);
        buf ^= 1;
    }

    const float qscale = 0.08838834764831845f;   // 1/sqrt(128), folded into Q
    const int f0 = n0 & 1023;
    const int h = f0 >> 7;
    const bool isV = (n0 >= 2048);
    const float sc = (n0 < 1024) ? qscale : 1.0f;
    short* dst = (n0 < 1024) ? Qh : Kh;

    #pragma unroll
    for (int half = 0; half < 2; ++half) {
        __syncthreads();
        if ((wave >> 1) == half) {
            #pragma unroll
            for (int i = 0; i < 4; ++i)
                #pragma unroll
                for (int j = 0; j < 4; ++j)
                    #pragma unroll
                    for (int p = 0; p < 4; ++p) {
                        int mr = i * 16 + quad * 4 + p;        // 0..63
                        int c = wn + j * 16 + l16;             // 0..127
                        short v = f2bf(acc[i][j][p] * sc);
                        if (isV) Cs[c * 68 + mr] = v;          // transposed
                        else     Cs[mr * 132 + c] = v;
                    }
        }
        __syncthreads();
        if (!isV) {
            #pragma unroll
            for (int jj = 0; jj < 4; ++jj) {
                int idx = tid + jj * 256;
                int row = idx >> 4;
                int chunk = idx & 15;
                int m = m0 + half * 64 + row;
                int bb = m >> 10, t = m & 1023;
                *(short8*)&dst[((h * 8 + bb) * 1024 + t) * 128 + chunk * 8] =
                    *(const short8*)&Cs[row * 132 + chunk * 8];
            }
        } else {
            int m = m0 + half * 64;
            int bb = m >> 10, t = m & 1023;
            #pragma unroll
            for (int jj = 0; jj < 4; ++jj) {
                int idx = tid + jj * 256;
                int dd = idx >> 3;
                int chunk = idx & 7;
                *(short8*)&VhT[((h * 8 + bb) * 128 + dd) * 1024 + t + chunk * 8] =
                    *(const short8*)&Cs[dd * 68 + chunk * 8];
            }
        }
    }
}

// ---------------------------------------------------------------------------
// Flash attention v4: causal-paired q-tiles (qt, 15-qt) per block -> balanced
// 17 subtile passes/block; K/V staged once via double-buffered global_load_lds
// prefetch (stage kt+1 during compute on kt). No running max (masked lanes
// underflow to 0 exactly like ref; row 1023 skips the -10000 add).
// K LDS: [kk(4)][row 64][32]; V LDS: [kk2(2)][dd 128][32]; both load_lds-laid.
// ---------------------------------------------------------------------------
#define LDP 70

__global__ __launch_bounds__(256) void attn_kernel(
    const short* __restrict__ Qh, const short* __restrict__ Kh,
    const short* __restrict__ VhT, const float* __restrict__ mask,
    float* __restrict__ out)
{
    __shared__ short Kb[2][8192];
    __shared__ short Vb[2][8192];
    __shared__ short Ps[4 * 16 * LDP];

    const int tid = threadIdx.x;
    const int qt = blockIdx.x;                // 0..7 ; pair (qt, 15-qt)
    const int hb = blockIdx.y;                // 0..63
    const int h = hb >> 3, b = hb & 7;

    const int wave = tid >> 6;
    const int lane = tid & 63;
    const int l16 = lane & 15;
    const int quad = lane >> 4;

    const int base = hb * 131072;
    const short* Qp = Qh + base;
    const short* Kp = Kh + base;
    const short* VTp = VhT + base;
    short* Pw = &Ps[wave * 16 * LDP];

    const int q0_lo = qt * 64 + wave * 16;            // wave's 16 rows, lo tile
    const int q0_hi = (15 - qt) * 64 + wave * 16;     // hi tile
    const int hi_start = 15 - qt;
    const bool hi_all = (qt == 0) && (wave == 3);     // wave containing row 1023

    // Q fragments (A-layout) straight from global
    short8 aq_lo[4], aq_hi[4];
    #pragma unroll
    for (int kk = 0; kk < 4; ++kk) {
        aq_lo[kk] = *(const short8*)(Qp + (q0_lo + l16) * 128 + kk * 32 + quad * 8);
        aq_hi[kk] = *(const short8*)(Qp + (q0_hi + l16) * 128 + kk * 32 + quad * 8);
    }

    floatx4 zero = {0.0f, 0.0f, 0.0f, 0.0f};
    floatx4 o_lo[8], o_hi[8];
    #pragma unroll
    for (int n = 0; n < 8; ++n) { o_lo[n] = zero; o_hi[n] = zero; }
    float l_lo[4] = {0, 0, 0, 0}, l_hi[4] = {0, 0, 0, 0};

    // stage K/V tile kt into buffer bf (8 global_load_lds per wave)
    auto stage = [&](int kt, int bf) {
        #pragma unroll
        for (int c = 0; c < 4; ++c) {
            int L = wave * 4 + c;                 // 0..15, wave-uniform
            int kk = L >> 2, rg = L & 3;
            load_lds_16B(Kp + (kt * 64 + rg * 16 + (lane >> 2)) * 128 + kk * 32 + (lane & 3) * 8,
                         &Kb[bf][kk * 2048 + rg * 512]);
        }
        #pragma unroll
        for (int c = 0; c < 4; ++c) {
            int L = wave * 4 + c;
            int kk2 = L >> 3, g = L & 7;
            load_lds_16B(VTp + (g * 16 + (lane >> 2)) * 1024 + kt * 64 + kk2 * 32 + (lane & 3) * 8,
                         &Vb[bf][kk2 * 4096 + g * 512]);
        }
    };

    // one q-group pass over the staged tile
    auto process = [&](int bf, int kt, const short8* aq, floatx4* o, float* l, int q0g) {
        floatx4 s[4];
        #pragma unroll
        for (int sub = 0; sub < 4; ++sub) {
            s[sub] = zero;
            #pragma unroll
            for (int kk = 0; kk < 4; ++kk) {
                short8 bk = *(const short8*)&Kb[bf][kk * 2048 + (sub * 16 + l16) * 32 + quad * 8];
                s[sub] = __builtin_amdgcn_mfma_f32_16x16x32_bf16(aq[kk], bk, s[sub], 0, 0, 0);
            }
        }
        #pragma unroll
        for (int sub = 0; sub < 4; ++sub)
            #pragma unroll
            for (int p = 0; p < 4; ++p) {
                int qg = q0g + quad * 4 + p;
                int kg = kt * 64 + sub * 16 + l16;
                float sv = s[sub][p];
                if (kg <= qg && qg != 1023) sv -= 10000.0f;
                float e = __expf(sv);
                l[p] += e;
                Pw[(quad * 4 + p) * LDP + sub * 16 + l16] = f2bf(e);
            }
        #pragma unroll
        for (int kk2 = 0; kk2 < 2; ++kk2) {
            short8 ap = *(const short8*)&Pw[l16 * LDP + kk2 * 32 + quad * 8];
            #pragma unroll
            for (int n = 0; n < 8; ++n) {
                short8 bv = *(const short8*)&Vb[bf][kk2 * 4096 + (n * 16 + l16) * 32 + quad * 8];
                o[n] = __builtin_amdgcn_mfma_f32_16x16x32_bf16(ap, bv, o[n], 0, 0, 0);
            }
        }
    };

    stage(qt, 0);
    int buf = 0;
    for (int kt = qt; kt < 16; ++kt) {
        __syncthreads();                           // buf ready
        if (kt + 1 < 16) stage(kt + 1, buf ^ 1);
        process(buf, kt, aq_lo, o_lo, l_lo, q0_lo);
        if (kt >= hi_start || hi_all)
            process(buf, kt, aq_hi, o_hi, l_hi, q0_hi);
        buf ^= 1;
    }

    // reduce l across the 16 col-lanes of each row
    #pragma unroll
    for (int off = 8; off >= 1; off >>= 1)
        #pragma unroll
        for (int p = 0; p < 4; ++p) {
            l_lo[p] += __shfl_xor(l_lo[p], off);
            l_hi[p] += __shfl_xor(l_hi[p], off);
        }

    #pragma unroll
    for (int p = 0; p < 4; ++p) {
        int qg = q0_lo + quad * 4 + p;
        float s = (1.0f / l_lo[p]) * mask[b * 1024 + qg];
        #pragma unroll
        for (int n = 0; n < 8; ++n)
            out[(b * 1024 + qg) * 1024 + h * 128 + n * 16 + l16] = o_lo[n][p] * s;
    }
    #pragma unroll
    for (int p = 0; p < 4; ++p) {
        int qg = q0_hi + quad * 4 + p;
        float s = (1.0f / l_hi[p]) * mask[b * 1024 + qg];
        #pragma unroll
        for (int n = 0; n < 8; ++n)
            out[(b * 1024 + qg) * 1024 + h * 128 + n * 16 + l16] = o_hi[n][p] * s;
    }
}

// ---------------------------------------------------------------------------
extern "C" void kernel_launch(void* const* d_in, const int* in_sizes, int n_in,
                              void* d_out, int out_size, void* d_ws, size_t ws_size,
                              hipStream_t stream) {
    const float* x    = (const float*)d_in[0];
    const float* mask = (const float*)d_in[1];
    const float* Wq   = (const float*)d_in[2];
    const float* Wk   = (const float*)d_in[3];
    const float* Wv   = (const float*)d_in[4];
    float* out = (float*)d_out;

    short* xb  = (short*)d_ws;            // 8388608
    short* wb  = xb + 8388608;            // 3145728 (Wq|Wk|Wv)
    short* Qh  = wb + 3145728;            // 8388608
    short* Kh  = Qh + 8388608;
    short* VhT = Kh + 8388608;

    cast_kernel<<<4096, 256, 0, stream>>>(x, xb, 1048576);
    cast3_kernel<<<1536, 256, 0, stream>>>(Wq, Wk, Wv, wb);
    qkv_gemm_kernel<<<dim3(24, 64), 256, 0, stream>>>(xb, wb, Qh, Kh, VhT);
    attn_kernel<<<dim3(8, 64), 256, 0, stream>>>(Qh, Kh, VhT, mask, out);
}

// Round 5
// 247.166 us; speedup vs baseline: 1.5979x; 1.0606x over previous
//
#include <hip/hip_runtime.h>
#include <hip/hip_bf16.h>
#include <stdint.h>

// B=8, T=1024, D=1024, H=8, d=128, M=8192.
// ws (shorts): xb[8388608] | wb[3145728] | Qh[8388608] | Kh[8388608] | VhT[8388608]
// Qh/Kh: [h][b][t][dd] bf16 (Qh pre-scaled by 1/sqrt(128)); VhT: [h][b][dd][t] bf16.

typedef __attribute__((ext_vector_type(8))) short short8;
typedef __attribute__((ext_vector_type(4))) float floatx4;

__device__ __forceinline__ short f2bf(float f) {
    union { float f; uint32_t u; } v; v.f = f;
    uint32_t r = v.u + 0x7fffu + ((v.u >> 16) & 1u);   // RNE
    return (short)(r >> 16);
}
__device__ __forceinline__ float bf2f(short u) {
    union { float f; uint32_t x; } v; v.x = ((uint32_t)(uint16_t)u) << 16;
    return v.f;
}

__device__ __forceinline__ void load_lds_16B(const void* g, void* l) {
    __builtin_amdgcn_global_load_lds(
        (const __attribute__((address_space(1))) void*)g,
        (__attribute__((address_space(3))) void*)l, 16, 0, 0);
}

// ---------------------------------------------------------------------------
// fp32 -> bf16 cast for x and Wq|Wk|Wv, one launch.
// blocks [0,4096): x ; [4096, 4096+1536): weights (512 blocks each).
// ---------------------------------------------------------------------------
__global__ __launch_bounds__(256) void cast_all_kernel(
    const float* __restrict__ x, const float* __restrict__ w0,
    const float* __restrict__ w1, const float* __restrict__ w2,
    short* __restrict__ xb, short* __restrict__ wb)
{
    int bid = blockIdx.x;
    const float* src;
    short* dst;
    int i;
    if (bid < 4096) {
        src = x; dst = xb; i = bid * 256 + threadIdx.x;
    } else {
        int sel = (bid - 4096) >> 9;
        int blk = (bid - 4096) & 511;
        src = (sel == 0) ? w0 : ((sel == 1) ? w1 : w2);
        dst = wb + sel * 1048576;
        i = blk * 256 + threadIdx.x;
    }
    float4 a = *(const float4*)(src + i * 8);
    float4 b = *(const float4*)(src + i * 8 + 4);
    short8 o;
    o[0] = f2bf(a.x); o[1] = f2bf(a.y); o[2] = f2bf(a.z); o[3] = f2bf(a.w);
    o[4] = f2bf(b.x); o[5] = f2bf(b.y); o[6] = f2bf(b.z); o[7] = f2bf(b.w);
    *(short8*)(dst + i * 8) = o;
}

// ---------------------------------------------------------------------------
// QKV GEMM, m97 structure + double-buffered prefetch.
// grid (m-tile 64, n-tile 24): same-m blocks land on one XCD (x-panel reuse).
// ---------------------------------------------------------------------------
__global__ __launch_bounds__(256) void qkv_gemm_kernel(
    const short* __restrict__ xb, const short* __restrict__ wb,
    short* __restrict__ Qh, short* __restrict__ Kh, short* __restrict__ VhT)
{
    __shared__ short As[2][4096];    // [buf][row 128][32]
    __shared__ short Bs[2][4096];
    __shared__ short Cs[8704];       // epilogue: 64x132 (Q/K) or 128x68 T (V)

    const int tid = threadIdx.x;
    const int m0 = blockIdx.x * 128;
    const int n0 = blockIdx.y * 128;
    const int wave = tid >> 6;
    const int lane = tid & 63;
    const int wm = (wave >> 1) * 64;
    const int wn = (wave & 1) * 64;
    const int l16 = lane & 15;
    const int quad = lane >> 4;
    const int srow = lane >> 2;
    const int scol = (lane & 3) * 8;

    floatx4 zero = {0.0f, 0.0f, 0.0f, 0.0f};
    floatx4 acc[4][4];
    for (int i = 0; i < 4; ++i)
        for (int j = 0; j < 4; ++j) acc[i][j] = zero;

    auto stage = [&](int k0, int bf) {
        #pragma unroll
        for (int c = 0; c < 4; ++c) {
            int chunk = wave * 4 + c;            // wave-uniform
            if (chunk < 8)
                load_lds_16B(xb + (m0 + chunk * 16 + srow) * 1024 + k0 + scol,
                             &As[bf][chunk * 512]);
            else
                load_lds_16B(wb + (n0 + (chunk - 8) * 16 + srow) * 1024 + k0 + scol,
                             &Bs[bf][(chunk - 8) * 512]);
        }
    };

    stage(0, 0);
    int buf = 0;
    for (int k0 = 0; k0 < 1024; k0 += 32) {
        __syncthreads();
        if (k0 + 32 < 1024) stage(k0 + 32, buf ^ 1);

        short8 a[4], b[4];
        #pragma unroll
        for (int i = 0; i < 4; ++i)
            a[i] = *(const short8*)&As[buf][(wm + i * 16 + l16) * 32 + quad * 8];
        #pragma unroll
        for (int j = 0; j < 4; ++j)
            b[j] = *(const short8*)&Bs[buf][(wn + j * 16 + l16) * 32 + quad * 8];
        #pragma unroll
        for (int i = 0; i < 4; ++i)
            #pragma unroll
            for (int j = 0; j < 4; ++j)
                acc[i][j] = __builtin_amdgcn_mfma_f32_16x16x32_bf16(a[i], b[j], acc[i][j], 0, 0, 0);
        buf ^= 1;
    }

    const float qscale = 0.08838834764831845f;   // 1/sqrt(128), folded into Q
    const int f0 = n0 & 1023;
    const int h = f0 >> 7;
    const bool isV = (n0 >= 2048);
    const float sc = (n0 < 1024) ? qscale : 1.0f;
    short* dst = (n0 < 1024) ? Qh : Kh;

    #pragma unroll
    for (int half = 0; half < 2; ++half) {
        __syncthreads();
        if ((wave >> 1) == half) {
            #pragma unroll
            for (int i = 0; i < 4; ++i)
                #pragma unroll
                for (int j = 0; j < 4; ++j)
                    #pragma unroll
                    for (int p = 0; p < 4; ++p) {
                        int mr = i * 16 + quad * 4 + p;        // 0..63
                        int c = wn + j * 16 + l16;             // 0..127
                        short v = f2bf(acc[i][j][p] * sc);
                        if (isV) Cs[c * 68 + mr] = v;          // transposed
                        else     Cs[mr * 132 + c] = v;
                    }
        }
        __syncthreads();
        if (!isV) {
            #pragma unroll
            for (int jj = 0; jj < 4; ++jj) {
                int idx = tid + jj * 256;
                int row = idx >> 4;
                int chunk = idx & 15;
                int m = m0 + half * 64 + row;
                int bb = m >> 10, t = m & 1023;
                *(short8*)&dst[((h * 8 + bb) * 1024 + t) * 128 + chunk * 8] =
                    *(const short8*)&Cs[row * 132 + chunk * 8];
            }
        } else {
            int m = m0 + half * 64;
            int bb = m >> 10, t = m & 1023;
            #pragma unroll
            for (int jj = 0; jj < 4; ++jj) {
                int idx = tid + jj * 256;
                int dd = idx >> 3;
                int chunk = idx & 7;
                *(short8*)&VhT[((h * 8 + bb) * 128 + dd) * 1024 + t + chunk * 8] =
                    *(const short8*)&Cs[dd * 68 + chunk * 8];
            }
        }
    }
}

// ---------------------------------------------------------------------------
// Flash attention v5: causal-paired q-tiles (qt, 15-qt), balanced 17 passes
// per wave (row 1023's full-range pass is delegated to row1023_kernel, which
// overwrites that row afterwards). lo/hi phases interleaved so S-MFMAs of one
// group hide the other's P LDS round-trip. grid (hb, qt): same-hb blocks on
// one XCD for K/V L2 locality.
// ---------------------------------------------------------------------------
#define LDP 70

__global__ __launch_bounds__(256) void attn_kernel(
    const short* __restrict__ Qh, const short* __restrict__ Kh,
    const short* __restrict__ VhT, const float* __restrict__ mask,
    float* __restrict__ out)
{
    __shared__ short Kb[2][8192];
    __shared__ short Vb[2][8192];
    __shared__ short Ps[4 * 16 * LDP];

    const int tid = threadIdx.x;
    const int hb = blockIdx.x;                // 0..63  -> XCD = hb%8
    const int qt = blockIdx.y;                // 0..7 ; pair (qt, 15-qt)
    const int h = hb >> 3, b = hb & 7;

    const int wave = tid >> 6;
    const int lane = tid & 63;
    const int l16 = lane & 15;
    const int quad = lane >> 4;

    const int base = hb * 131072;
    const short* Qp = Qh + base;
    const short* Kp = Kh + base;
    const short* VTp = VhT + base;
    short* Pw = &Ps[wave * 16 * LDP];

    const int q0_lo = qt * 64 + wave * 16;
    const int q0_hi = (15 - qt) * 64 + wave * 16;
    const int hi_start = 15 - qt;

    short8 aq_lo[4], aq_hi[4];
    #pragma unroll
    for (int kk = 0; kk < 4; ++kk) {
        aq_lo[kk] = *(const short8*)(Qp + (q0_lo + l16) * 128 + kk * 32 + quad * 8);
        aq_hi[kk] = *(const short8*)(Qp + (q0_hi + l16) * 128 + kk * 32 + quad * 8);
    }

    floatx4 zero = {0.0f, 0.0f, 0.0f, 0.0f};
    floatx4 o_lo[8], o_hi[8];
    #pragma unroll
    for (int n = 0; n < 8; ++n) { o_lo[n] = zero; o_hi[n] = zero; }
    float l_lo[4] = {0, 0, 0, 0}, l_hi[4] = {0, 0, 0, 0};

    auto stage = [&](int kt, int bf) {
        #pragma unroll
        for (int c = 0; c < 4; ++c) {
            int L = wave * 4 + c;
            int kk = L >> 2, rg = L & 3;
            load_lds_16B(Kp + (kt * 64 + rg * 16 + (lane >> 2)) * 128 + kk * 32 + (lane & 3) * 8,
                         &Kb[bf][kk * 2048 + rg * 512]);
        }
        #pragma unroll
        for (int c = 0; c < 4; ++c) {
            int L = wave * 4 + c;
            int kk2 = L >> 3, g = L & 7;
            load_lds_16B(VTp + (g * 16 + (lane >> 2)) * 1024 + kt * 64 + kk2 * 32 + (lane & 3) * 8,
                         &Vb[bf][kk2 * 4096 + g * 512]);
        }
    };

    auto s_phase = [&](int bf, const short8* aq, floatx4* s) {
        #pragma unroll
        for (int sub = 0; sub < 4; ++sub) {
            s[sub] = zero;
            #pragma unroll
            for (int kk = 0; kk < 4; ++kk) {
                short8 bk = *(const short8*)&Kb[bf][kk * 2048 + (sub * 16 + l16) * 32 + quad * 8];
                s[sub] = __builtin_amdgcn_mfma_f32_16x16x32_bf16(aq[kk], bk, s[sub], 0, 0, 0);
            }
        }
    };
    auto exp_phase = [&](floatx4* s, int q0g, float* l, int kt) {
        #pragma unroll
        for (int sub = 0; sub < 4; ++sub)
            #pragma unroll
            for (int p = 0; p < 4; ++p) {
                int qg = q0g + quad * 4 + p;
                int kg = kt * 64 + sub * 16 + l16;
                float sv = s[sub][p];
                if (kg <= qg && qg != 1023) sv -= 10000.0f;
                float e = __expf(sv);
                l[p] += e;
                Pw[(quad * 4 + p) * LDP + sub * 16 + l16] = f2bf(e);
            }
    };
    auto pv_phase = [&](int bf, floatx4* o) {
        #pragma unroll
        for (int kk2 = 0; kk2 < 2; ++kk2) {
            short8 ap = *(const short8*)&Pw[l16 * LDP + kk2 * 32 + quad * 8];
            #pragma unroll
            for (int n = 0; n < 8; ++n) {
                short8 bv = *(const short8*)&Vb[bf][kk2 * 4096 + (n * 16 + l16) * 32 + quad * 8];
                o[n] = __builtin_amdgcn_mfma_f32_16x16x32_bf16(ap, bv, o[n], 0, 0, 0);
            }
        }
    };

    stage(qt, 0);
    int buf = 0;
    for (int kt = qt; kt < 16; ++kt) {
        __syncthreads();
        if (kt + 1 < 16) stage(kt + 1, buf ^ 1);
        const bool do_hi = (kt >= hi_start);
        floatx4 s_lo[4], s_hi[4];
        s_phase(buf, aq_lo, s_lo);
        exp_phase(s_lo, q0_lo, l_lo, kt);
        if (do_hi) s_phase(buf, aq_hi, s_hi);     // hides lo's P round-trip
        pv_phase(buf, o_lo);
        if (do_hi) {
            exp_phase(s_hi, q0_hi, l_hi, kt);     // in-order DS => WAR safe
            pv_phase(buf, o_hi);
        }
        buf ^= 1;
    }

    #pragma unroll
    for (int off = 8; off >= 1; off >>= 1)
        #pragma unroll
        for (int p = 0; p < 4; ++p) {
            l_lo[p] += __shfl_xor(l_lo[p], off);
            l_hi[p] += __shfl_xor(l_hi[p], off);
        }

    #pragma unroll
    for (int p = 0; p < 4; ++p) {
        int qg = q0_lo + quad * 4 + p;
        float s = (1.0f / l_lo[p]) * mask[b * 1024 + qg];
        #pragma unroll
        for (int n = 0; n < 8; ++n)
            out[(b * 1024 + qg) * 1024 + h * 128 + n * 16 + l16] = o_lo[n][p] * s;
    }
    #pragma unroll
    for (int p = 0; p < 4; ++p) {
        int qg = q0_hi + quad * 4 + p;
        float s = (1.0f / l_hi[p]) * mask[b * 1024 + qg];
        #pragma unroll
        for (int n = 0; n < 8; ++n)
            out[(b * 1024 + qg) * 1024 + h * 128 + n * 16 + l16] = o_hi[n][p] * s;
    }
}

// ---------------------------------------------------------------------------
// Row 1023 (fully-masked row => plain softmax over all 1024 keys, shift-
// invariance). One block per hb; overwrites attn_kernel's placeholder row.
// ---------------------------------------------------------------------------
__global__ __launch_bounds__(256) void row1023_kernel(
    const short* __restrict__ Qh, const short* __restrict__ Kh,
    const short* __restrict__ VhT, const float* __restrict__ mask,
    float* __restrict__ out)
{
    __shared__ float qv[128];
    __shared__ float ps[1024];
    __shared__ float red[4];

    const int hb = blockIdx.x;
    const int h = hb >> 3, b = hb & 7;
    const int base = hb * 131072;
    const int tid = threadIdx.x;
    const int wave = tid >> 6, lane = tid & 63;

    if (tid < 128) qv[tid] = bf2f(Qh[base + 1023 * 128 + tid]);  // pre-scaled
    __syncthreads();

    // scores + exp for keys 4*tid .. 4*tid+3
    float tot = 0.0f;
    #pragma unroll
    for (int kk = 0; kk < 4; ++kk) {
        int k = tid * 4 + kk;
        const short8* kr = (const short8*)(Kh + base + k * 128);
        float acc = 0.0f;
        #pragma unroll
        for (int c = 0; c < 16; ++c) {
            short8 v = kr[c];
            #pragma unroll
            for (int j = 0; j < 8; ++j) acc += qv[c * 8 + j] * bf2f(v[j]);
        }
        float e = __expf(acc);
        ps[k] = e;
        tot += e;
    }
    #pragma unroll
    for (int off = 32; off >= 1; off >>= 1) tot += __shfl_xor(tot, off);
    if (lane == 0) red[wave] = tot;
    __syncthreads();
    float inv = 1.0f / (red[0] + red[1] + red[2] + red[3]);
    inv *= mask[b * 1024 + 1023];

    // O[dd] = sum_k ps[k] * V[k][dd]; 2 threads per dd
    int dd = tid >> 1, half = tid & 1;
    const short* vr = VhT + base + dd * 1024 + half * 512;
    const float* pp = ps + half * 512;
    float acc = 0.0f;
    for (int k = 0; k < 512; k += 8) {
        short8 v = *(const short8*)(vr + k);
        #pragma unroll
        for (int j = 0; j < 8; ++j) acc += pp[k + j] * bf2f(v[j]);
    }
    acc += __shfl_xor(acc, 1);
    if (half == 0)
        out[(b * 1024 + 1023) * 1024 + h * 128 + dd] = acc * inv;
}

// ---------------------------------------------------------------------------
extern "C" void kernel_launch(void* const* d_in, const int* in_sizes, int n_in,
                              void* d_out, int out_size, void* d_ws, size_t ws_size,
                              hipStream_t stream) {
    const float* x    = (const float*)d_in[0];
    const float* mask = (const float*)d_in[1];
    const float* Wq   = (const float*)d_in[2];
    const float* Wk   = (const float*)d_in[3];
    const float* Wv   = (const float*)d_in[4];
    float* out = (float*)d_out;

    short* xb  = (short*)d_ws;            // 8388608
    short* wb  = xb + 8388608;            // 3145728 (Wq|Wk|Wv)
    short* Qh  = wb + 3145728;            // 8388608
    short* Kh  = Qh + 8388608;
    short* VhT = Kh + 8388608;

    cast_all_kernel<<<5632, 256, 0, stream>>>(x, Wq, Wk, Wv, xb, wb);
    qkv_gemm_kernel<<<dim3(64, 24), 256, 0, stream>>>(xb, wb, Qh, Kh, VhT);
    attn_kernel<<<dim3(64, 8), 256, 0, stream>>>(Qh, Kh, VhT, mask, out);
    row1023_kernel<<<64, 256, 0, stream>>>(Qh, Kh, VhT, mask, out);
}

// Round 6
// 238.199 us; speedup vs baseline: 1.6580x; 1.0376x over previous
//
#include <hip/hip_runtime.h>
#include <hip/hip_bf16.h>
#include <stdint.h>

// B=8, T=1024, D=1024, H=8, d=128, M=8192.
// ws (shorts): xb[8388608] | wb[3145728] | Qh[8388608] | Kh[8388608] | VhT[8388608]
// Qh/Kh: [h][b][t][dd] bf16 (Qh pre-scaled by 1/sqrt(128)); VhT: [h][b][dd][t] bf16.
//
// LDS staging uses an XOR swizzle so ds_read_b128 fragment reads are 2-way
// (free) instead of 8-way: stage lane i loads global colblock (i&3)^((i>>3)&3);
// readers use colblock quad^((l16>>1)&3).

typedef __attribute__((ext_vector_type(8))) short short8;
typedef __attribute__((ext_vector_type(4))) float floatx4;

__device__ __forceinline__ short f2bf(float f) {
    union { float f; uint32_t u; } v; v.f = f;
    uint32_t r = v.u + 0x7fffu + ((v.u >> 16) & 1u);   // RNE
    return (short)(r >> 16);
}
__device__ __forceinline__ float bf2f(short u) {
    union { float f; uint32_t x; } v; v.x = ((uint32_t)(uint16_t)u) << 16;
    return v.f;
}

__device__ __forceinline__ void load_lds_16B(const void* g, void* l) {
    __builtin_amdgcn_global_load_lds(
        (const __attribute__((address_space(1))) void*)g,
        (__attribute__((address_space(3))) void*)l, 16, 0, 0);
}

// ---------------------------------------------------------------------------
// fp32 -> bf16 cast for x and Wq|Wk|Wv, one launch.
// ---------------------------------------------------------------------------
__global__ __launch_bounds__(256) void cast_all_kernel(
    const float* __restrict__ x, const float* __restrict__ w0,
    const float* __restrict__ w1, const float* __restrict__ w2,
    short* __restrict__ xb, short* __restrict__ wb)
{
    int bid = blockIdx.x;
    const float* src;
    short* dst;
    int i;
    if (bid < 4096) {
        src = x; dst = xb; i = bid * 256 + threadIdx.x;
    } else {
        int sel = (bid - 4096) >> 9;
        int blk = (bid - 4096) & 511;
        src = (sel == 0) ? w0 : ((sel == 1) ? w1 : w2);
        dst = wb + sel * 1048576;
        i = blk * 256 + threadIdx.x;
    }
    float4 a = *(const float4*)(src + i * 8);
    float4 b = *(const float4*)(src + i * 8 + 4);
    short8 o;
    o[0] = f2bf(a.x); o[1] = f2bf(a.y); o[2] = f2bf(a.z); o[3] = f2bf(a.w);
    o[4] = f2bf(b.x); o[5] = f2bf(b.y); o[6] = f2bf(b.z); o[7] = f2bf(b.w);
    *(short8*)(dst + i * 8) = o;
}

// ---------------------------------------------------------------------------
// QKV GEMM: m97 structure + dbuf prefetch + XOR-swizzled LDS + Cs aliased
// over As/Bs (32 KB LDS -> 5 blocks/CU).
// ---------------------------------------------------------------------------
__global__ __launch_bounds__(256) void qkv_gemm_kernel(
    const short* __restrict__ xb, const short* __restrict__ wb,
    short* __restrict__ Qh, short* __restrict__ Kh, short* __restrict__ VhT)
{
    __shared__ short smem[16384];    // As[2][4096] | Bs[2][4096]; Cs aliases
    short* As = smem;                // As[bf] = smem + bf*4096
    short* Bs = smem + 8192;
    short* Cs = smem;                // epilogue: 64x132 (Q/K) or 128x68 T (V)

    const int tid = threadIdx.x;
    const int m0 = blockIdx.x * 128;
    const int n0 = blockIdx.y * 128;
    const int wave = tid >> 6;
    const int lane = tid & 63;
    const int wm = (wave >> 1) * 64;
    const int wn = (wave & 1) * 64;
    const int l16 = lane & 15;
    const int quad = lane >> 4;
    const int srow = lane >> 2;
    const int scb = ((lane & 3) ^ ((lane >> 3) & 3)) * 8;     // swizzled stage col
    const int rq  = (quad ^ ((l16 >> 1) & 3)) * 8;            // swizzled read col

    floatx4 zero = {0.0f, 0.0f, 0.0f, 0.0f};
    floatx4 acc[4][4];
    for (int i = 0; i < 4; ++i)
        for (int j = 0; j < 4; ++j) acc[i][j] = zero;

    auto stage = [&](int k0, int bf) {
        #pragma unroll
        for (int c = 0; c < 4; ++c) {
            int chunk = wave * 4 + c;            // wave-uniform
            if (chunk < 8)
                load_lds_16B(xb + (m0 + chunk * 16 + srow) * 1024 + k0 + scb,
                             &As[bf * 4096 + chunk * 512]);
            else
                load_lds_16B(wb + (n0 + (chunk - 8) * 16 + srow) * 1024 + k0 + scb,
                             &Bs[bf * 4096 + (chunk - 8) * 512]);
        }
    };

    stage(0, 0);
    int buf = 0;
    for (int k0 = 0; k0 < 1024; k0 += 32) {
        __syncthreads();
        if (k0 + 32 < 1024) stage(k0 + 32, buf ^ 1);

        short8 a[4], b[4];
        #pragma unroll
        for (int i = 0; i < 4; ++i)
            a[i] = *(const short8*)&As[buf * 4096 + (wm + i * 16 + l16) * 32 + rq];
        #pragma unroll
        for (int j = 0; j < 4; ++j)
            b[j] = *(const short8*)&Bs[buf * 4096 + (wn + j * 16 + l16) * 32 + rq];
        #pragma unroll
        for (int i = 0; i < 4; ++i)
            #pragma unroll
            for (int j = 0; j < 4; ++j)
                acc[i][j] = __builtin_amdgcn_mfma_f32_16x16x32_bf16(a[i], b[j], acc[i][j], 0, 0, 0);
        buf ^= 1;
    }

    const float qscale = 0.08838834764831845f;   // 1/sqrt(128), folded into Q
    const int f0 = n0 & 1023;
    const int h = f0 >> 7;
    const bool isV = (n0 >= 2048);
    const float sc = (n0 < 1024) ? qscale : 1.0f;
    short* dst = (n0 < 1024) ? Qh : Kh;

    #pragma unroll
    for (int half = 0; half < 2; ++half) {
        __syncthreads();
        if ((wave >> 1) == half) {
            #pragma unroll
            for (int i = 0; i < 4; ++i)
                #pragma unroll
                for (int j = 0; j < 4; ++j)
                    #pragma unroll
                    for (int p = 0; p < 4; ++p) {
                        int mr = i * 16 + quad * 4 + p;        // 0..63
                        int c = wn + j * 16 + l16;             // 0..127
                        short v = f2bf(acc[i][j][p] * sc);
                        if (isV) Cs[c * 68 + mr] = v;          // transposed
                        else     Cs[mr * 132 + c] = v;
                    }
        }
        __syncthreads();
        if (!isV) {
            #pragma unroll
            for (int jj = 0; jj < 4; ++jj) {
                int idx = tid + jj * 256;
                int row = idx >> 4;
                int chunk = idx & 15;
                int m = m0 + half * 64 + row;
                int bb = m >> 10, t = m & 1023;
                *(short8*)&dst[((h * 8 + bb) * 1024 + t) * 128 + chunk * 8] =
                    *(const short8*)&Cs[row * 132 + chunk * 8];
            }
        } else {
            int m = m0 + half * 64;
            int bb = m >> 10, t = m & 1023;
            #pragma unroll
            for (int jj = 0; jj < 4; ++jj) {
                int idx = tid + jj * 256;
                int dd = idx >> 3;
                int chunk = idx & 7;
                *(short8*)&VhT[((h * 8 + bb) * 128 + dd) * 1024 + t + chunk * 8] =
                    *(const short8*)&Cs[dd * 68 + chunk * 8];
            }
        }
    }
}

// ---------------------------------------------------------------------------
// Flash attention v6: causal-paired q-tiles (qt, 15-qt), balanced 17 passes;
// XOR-swizzled K/V staging; row 1023 handled by qt==8 blocks in the SAME
// launch (main path never stores qg==1023).
// ---------------------------------------------------------------------------
#define LDP 70

__global__ __launch_bounds__(256) void attn_kernel(
    const short* __restrict__ Qh, const short* __restrict__ Kh,
    const short* __restrict__ VhT, const float* __restrict__ mask,
    float* __restrict__ out)
{
    __shared__ short Kb[2][8192];
    __shared__ short Vb[2][8192];
    __shared__ short Ps[4 * 16 * LDP];

    const int tid = threadIdx.x;
    const int hb = blockIdx.x;                // 0..63  -> XCD = hb%8
    const int qt = blockIdx.y;                // 0..7 pair (qt,15-qt); 8 = row1023
    const int h = hb >> 3, b = hb & 7;
    const int base = hb * 131072;

    if (qt == 8) {
        // ---- row 1023: plain softmax over all 1024 keys (shift-invariance) ----
        float* qv = (float*)&Kb[0][0];        // 128 floats
        float* ps = qv + 128;                 // 1024 floats
        float* red = ps + 1024;               // 4 floats
        const int wave = tid >> 6, lane = tid & 63;

        if (tid < 128) qv[tid] = bf2f(Qh[base + 1023 * 128 + tid]);  // pre-scaled
        __syncthreads();

        float tot = 0.0f;
        #pragma unroll
        for (int kk = 0; kk < 4; ++kk) {
            int k = tid * 4 + kk;
            const short8* kr = (const short8*)(Kh + base + k * 128);
            float acc = 0.0f;
            #pragma unroll
            for (int c = 0; c < 16; ++c) {
                short8 v = kr[c];
                #pragma unroll
                for (int j = 0; j < 8; ++j) acc += qv[c * 8 + j] * bf2f(v[j]);
            }
            float e = __expf(acc);
            ps[k] = e;
            tot += e;
        }
        #pragma unroll
        for (int off = 32; off >= 1; off >>= 1) tot += __shfl_xor(tot, off);
        if (lane == 0) red[wave] = tot;
        __syncthreads();
        float inv = 1.0f / (red[0] + red[1] + red[2] + red[3]);
        inv *= mask[b * 1024 + 1023];

        int dd = tid >> 1, half = tid & 1;
        const short* vr = VhT + base + dd * 1024 + half * 512;
        const float* pp = ps + half * 512;
        float acc = 0.0f;
        for (int k = 0; k < 512; k += 8) {
            short8 v = *(const short8*)(vr + k);
            #pragma unroll
            for (int j = 0; j < 8; ++j) acc += pp[k + j] * bf2f(v[j]);
        }
        acc += __shfl_xor(acc, 1);
        if (half == 0)
            out[(b * 1024 + 1023) * 1024 + h * 128 + dd] = acc * inv;
        return;
    }

    const int wave = tid >> 6;
    const int lane = tid & 63;
    const int l16 = lane & 15;
    const int quad = lane >> 4;
    const int srow = lane >> 2;
    const int scb = ((lane & 3) ^ ((lane >> 3) & 3)) * 8;
    const int rq  = (quad ^ ((l16 >> 1) & 3)) * 8;

    const short* Qp = Qh + base;
    const short* Kp = Kh + base;
    const short* VTp = VhT + base;
    short* Pw = &Ps[wave * 16 * LDP];

    const int q0_lo = qt * 64 + wave * 16;
    const int q0_hi = (15 - qt) * 64 + wave * 16;
    const int hi_start = 15 - qt;

    short8 aq_lo[4], aq_hi[4];
    #pragma unroll
    for (int kk = 0; kk < 4; ++kk) {
        aq_lo[kk] = *(const short8*)(Qp + (q0_lo + l16) * 128 + kk * 32 + quad * 8);
        aq_hi[kk] = *(const short8*)(Qp + (q0_hi + l16) * 128 + kk * 32 + quad * 8);
    }

    floatx4 zero = {0.0f, 0.0f, 0.0f, 0.0f};
    floatx4 o_lo[8], o_hi[8];
    #pragma unroll
    for (int n = 0; n < 8; ++n) { o_lo[n] = zero; o_hi[n] = zero; }
    float l_lo[4] = {0, 0, 0, 0}, l_hi[4] = {0, 0, 0, 0};

    auto stage = [&](int kt, int bf) {
        #pragma unroll
        for (int c = 0; c < 4; ++c) {
            int L = wave * 4 + c;
            int kk = L >> 2, rg = L & 3;
            load_lds_16B(Kp + (kt * 64 + rg * 16 + srow) * 128 + kk * 32 + scb,
                         &Kb[bf][kk * 2048 + rg * 512]);
        }
        #pragma unroll
        for (int c = 0; c < 4; ++c) {
            int L = wave * 4 + c;
            int kk2 = L >> 3, g = L & 7;
            load_lds_16B(VTp + (g * 16 + srow) * 1024 + kt * 64 + kk2 * 32 + scb,
                         &Vb[bf][kk2 * 4096 + g * 512]);
        }
    };

    auto s_phase = [&](int bf, const short8* aq, floatx4* s) {
        #pragma unroll
        for (int sub = 0; sub < 4; ++sub) {
            s[sub] = zero;
            #pragma unroll
            for (int kk = 0; kk < 4; ++kk) {
                short8 bk = *(const short8*)&Kb[bf][kk * 2048 + (sub * 16 + l16) * 32 + rq];
                s[sub] = __builtin_amdgcn_mfma_f32_16x16x32_bf16(aq[kk], bk, s[sub], 0, 0, 0);
            }
        }
    };
    auto exp_phase = [&](floatx4* s, int q0g, float* l, int kt) {
        #pragma unroll
        for (int sub = 0; sub < 4; ++sub)
            #pragma unroll
            for (int p = 0; p < 4; ++p) {
                int qg = q0g + quad * 4 + p;
                int kg = kt * 64 + sub * 16 + l16;
                float sv = s[sub][p];
                if (kg <= qg && qg != 1023) sv -= 10000.0f;
                float e = __expf(sv);
                l[p] += e;
                Pw[(quad * 4 + p) * LDP + sub * 16 + l16] = f2bf(e);
            }
    };
    auto pv_phase = [&](int bf, floatx4* o) {
        #pragma unroll
        for (int kk2 = 0; kk2 < 2; ++kk2) {
            short8 ap = *(const short8*)&Pw[l16 * LDP + kk2 * 32 + quad * 8];
            #pragma unroll
            for (int n = 0; n < 8; ++n) {
                short8 bv = *(const short8*)&Vb[bf][kk2 * 4096 + (n * 16 + l16) * 32 + rq];
                o[n] = __builtin_amdgcn_mfma_f32_16x16x32_bf16(ap, bv, o[n], 0, 0, 0);
            }
        }
    };

    stage(qt, 0);
    int buf = 0;
    for (int kt = qt; kt < 16; ++kt) {
        __syncthreads();
        if (kt + 1 < 16) stage(kt + 1, buf ^ 1);
        const bool do_hi = (kt >= hi_start);
        floatx4 s_lo[4], s_hi[4];
        s_phase(buf, aq_lo, s_lo);
        exp_phase(s_lo, q0_lo, l_lo, kt);
        if (do_hi) s_phase(buf, aq_hi, s_hi);     // hides lo's P round-trip
        pv_phase(buf, o_lo);
        if (do_hi) {
            exp_phase(s_hi, q0_hi, l_hi, kt);     // in-order DS => WAR safe
            pv_phase(buf, o_hi);
        }
        buf ^= 1;
    }

    #pragma unroll
    for (int off = 8; off >= 1; off >>= 1)
        #pragma unroll
        for (int p = 0; p < 4; ++p) {
            l_lo[p] += __shfl_xor(l_lo[p], off);
            l_hi[p] += __shfl_xor(l_hi[p], off);
        }

    #pragma unroll
    for (int p = 0; p < 4; ++p) {
        int qg = q0_lo + quad * 4 + p;
        float s = (1.0f / l_lo[p]) * mask[b * 1024 + qg];
        #pragma unroll
        for (int n = 0; n < 8; ++n)
            out[(b * 1024 + qg) * 1024 + h * 128 + n * 16 + l16] = o_lo[n][p] * s;
    }
    #pragma unroll
    for (int p = 0; p < 4; ++p) {
        int qg = q0_hi + quad * 4 + p;
        if (qg == 1023) continue;                 // written by qt==8 block
        float s = (1.0f / l_hi[p]) * mask[b * 1024 + qg];
        #pragma unroll
        for (int n = 0; n < 8; ++n)
            out[(b * 1024 + qg) * 1024 + h * 128 + n * 16 + l16] = o_hi[n][p] * s;
    }
}

// ---------------------------------------------------------------------------
extern "C" void kernel_launch(void* const* d_in, const int* in_sizes, int n_in,
                              void* d_out, int out_size, void* d_ws, size_t ws_size,
                              hipStream_t stream) {
    const float* x    = (const float*)d_in[0];
    const float* mask = (const float*)d_in[1];
    const float* Wq   = (const float*)d_in[2];
    const float* Wk   = (const float*)d_in[3];
    const float* Wv   = (const float*)d_in[4];
    float* out = (float*)d_out;

    short* xb  = (short*)d_ws;            // 8388608
    short* wb  = xb + 8388608;            // 3145728 (Wq|Wk|Wv)
    short* Qh  = wb + 3145728;            // 8388608
    short* Kh  = Qh + 8388608;
    short* VhT = Kh + 8388608;

    cast_all_kernel<<<5632, 256, 0, stream>>>(x, Wq, Wk, Wv, xb, wb);
    qkv_gemm_kernel<<<dim3(64, 24), 256, 0, stream>>>(xb, wb, Qh, Kh, VhT);
    attn_kernel<<<dim3(64, 9), 256, 0, stream>>>(Qh, Kh, VhT, mask, out);
}